// Round 7
// baseline (478.217 us; speedup 1.0000x reference)
//
#include <hip/hip_runtime.h>
#include <cstdint>
#include <cstddef>

// Problem constants (FusedExperts: E=8 TOPK=2, B=2 S=4096 D=1024 H=2048)
#define TT   8192     // tokens = B*S
#define DD   1024     // model dim
#define HH   2048     // hidden dim
#define H2   4096     // 2*H
#define EE   8        // experts
#define PP   16384    // routed pairs = TT*TOPK
#define PADROWS 17280 // max sum of per-expert 128-padded group sizes = 135*128
#define MAXTILES 135

typedef unsigned short u16;
typedef __attribute__((ext_vector_type(8))) short bf16x8;   // 8 bf16 = 4 VGPR (MFMA A/B frag)
typedef __attribute__((ext_vector_type(8))) unsigned short u16x8;
typedef __attribute__((ext_vector_type(4))) float f32x4;    // MFMA C/D frag

__device__ __forceinline__ u16 f2bf(float f) {
  unsigned int u = __builtin_bit_cast(unsigned int, f);
  u += 0x7fffu + ((u >> 16) & 1u);          // round-to-nearest-even
  return (u16)(u >> 16);
}
__device__ __forceinline__ float bf2f(u16 s) {
  unsigned int u = ((unsigned int)s) << 16;
  return __builtin_bit_cast(float, u);
}

__device__ __forceinline__ void gload_lds16(const u16* g, u16* l) {
  __builtin_amdgcn_global_load_lds(
      (const __attribute__((address_space(1))) void*)g,
      (__attribute__((address_space(3))) void*)l, 16, 0, 0);
}

// ---------------- casts ----------------
__global__ void cast_x_kernel(const float* __restrict__ x, u16* __restrict__ xb) {
  const long i = (long)blockIdx.x * 256 + threadIdx.x;  // one thread -> 8 elems
  const f32x4* s = (const f32x4*)(x + i * 8);
  f32x4 a = s[0], b = s[1];
  u16x8 o;
  o[0]=f2bf(a[0]); o[1]=f2bf(a[1]); o[2]=f2bf(a[2]); o[3]=f2bf(a[3]);
  o[4]=f2bf(b[0]); o[5]=f2bf(b[1]); o[6]=f2bf(b[2]); o[7]=f2bf(b[3]);
  *(u16x8*)(xb + i * 8) = o;
}

// src [E][R][C] f32 -> dst [E][C][R] bf16, vectorized 256B-contiguous writes.
__global__ void tcast_kernel(const float* __restrict__ src, u16* __restrict__ dst,
                             int R, int C) {
  __shared__ __align__(16) u16 tile[32][140];
  const long base = (long)blockIdx.z * (long)R * C;
  const int c0 = blockIdx.x * 32, r0 = blockIdx.y * 128;
  const int t = threadIdx.x;
  {
    const int tx = t & 31;          // col
    const int ty = t >> 5;          // row 0..7 (+8*rr)
#pragma unroll
    for (int rr = 0; rr < 16; ++rr) {
      const int r = ty + rr * 8;
      tile[tx][r] = f2bf(src[base + (long)(r0 + r) * C + c0 + tx]);
    }
  }
  __syncthreads();
  {
    const int k = t & 15;           // chunk within row: r8 = 8k
    const int cb = t >> 4;          // 0..15
#pragma unroll
    for (int i = 0; i < 2; ++i) {
      const int c = i * 16 + cb;
      u16x8 o = *(const u16x8*)(&tile[c][8 * k]);
      *(u16x8*)(dst + base + (long)(c0 + c) * R + r0 + 8 * k) = o;
    }
  }
}

// ---------------- routing ----------------
__global__ void count_kernel(const int* __restrict__ eidx, int* __restrict__ cnt) {
  int i = blockIdx.x * 256 + threadIdx.x;
  if (i < PP) atomicAdd(&cnt[eidx[i]], 1);
}
__global__ void scan_kernel(const int* __restrict__ cnt, int* __restrict__ pofs) {
  if (threadIdx.x == 0 && blockIdx.x == 0) {
    int run = 0;
    for (int e = 0; e < EE; ++e) { pofs[e] = run; run += ((cnt[e] + 127) >> 7) << 7; }
    pofs[EE] = run;
  }
}
__global__ void place_kernel(const int* __restrict__ eidx, const float* __restrict__ p,
                             const int* __restrict__ pofs, int* __restrict__ cnt2,
                             int* __restrict__ ptok, float* __restrict__ pscale,
                             int* __restrict__ ppos) {
  int i = blockIdx.x * 256 + threadIdx.x;
  if (i < PP) {
    int e = eidx[i];
    int r = atomicAdd(&cnt2[e], 1);
    int pos = pofs[e] + r;
    ptok[pos] = i >> 1;       // token index (TOPK=2)
    pscale[pos] = p[i];
    ppos[i] = pos;
  }
}

// ============ GEMM cores: proven 2-barrier skeleton, WIDE per-wave tiles ============
// Per-wave output 64x128 (was 64x64): A-frag reused over 8 n-frags ->
// 24 ds_read_b128 per 64 MFMA (0.375 r/M, was 0.5) -> LDS-pipe demand under peak.
// LDS: A[128][64] bf16 (16KB) + B[256][64] (32KB) = 48KB -> 3 blocks/CU.
// Swizzle: (row,slot) at slot^(row&7); gload_lds linear dest + inverse-swizzled
// global source; ds_read applies same XOR (proven R2-R6, conflicts == 0).

// GEMM1: hb[pos, 0:H] = silu(g)*h where hg = x[tok] @ w13[e]
// Block: 128 rows x (128 h-cols + 128 g-cols). B-tile rows: 0-127 = h cols
// [j*128..+128), 128-255 = g cols (same range + HH). Wave (wr,wc) of 2x2:
// rows [wr*64,+64), n-frags 0-3 = h at cols wc*64+n*16, 4-7 = g same cols.
__global__ __launch_bounds__(256, 2)
void gemm1_kernel(const u16* __restrict__ xb, const u16* __restrict__ w13t,
                  const int* __restrict__ ptok, const int* __restrict__ pofs,
                  u16* __restrict__ hb) {
  __shared__ __align__(16) u16 lds_a[128 * 64];
  __shared__ __align__(16) u16 lds_b[256 * 64];

  // T1 XCD swizzle: nwg = 135*16 = 2160 = 8*270 (exact); tile-fast, j-slow per XCD
  const int f = blockIdx.y * MAXTILES + blockIdx.x;
  const int wg = (f & 7) * 270 + (f >> 3);
  const int tileIdx = wg % MAXTILES;
  const int j = wg / MAXTILES;              // 0..15: h cols [j*128, +128)

  const int ts = tileIdx * 128;
  if (ts >= pofs[EE]) return;
  int e = 0;
#pragma unroll
  for (int i = 1; i < EE; ++i) e += (ts >= pofs[i]) ? 1 : 0;

  const int tid = threadIdx.x;
  const int w = tid >> 6, lane = tid & 63;
  const int wr = w >> 1, wc = w & 1;

  const u16* bbase = w13t + (long)e * ((long)H2 * DD);

  // --- staging: A 4 rounds, B 8 rounds; 16B per lane per round ---
  const u16* asrc[4]; const u16* bsrc[8];
  u16* adst[4]; u16* bdst[8];
#pragma unroll
  for (int r = 0; r < 4; ++r) {
    const int L = r * 4096 + tid * 16;                   // byte in A region
    const int row = L >> 7;
    const int slot = ((L >> 4) & 7) ^ (row & 7);
    asrc[r] = xb + (long)ptok[ts + row] * DD + slot * 8;
    adst[r] = lds_a + r * 2048 + w * 512;                // wave-uniform base
  }
#pragma unroll
  for (int r = 0; r < 8; ++r) {
    const int L = r * 4096 + tid * 16;                   // byte in B region
    const int row = L >> 7;                              // 0..255
    const int slot = ((L >> 4) & 7) ^ (row & 7);
    const int grow = (row < 128) ? (j * 128 + row) : (HH + j * 128 + row - 128);
    bsrc[r] = bbase + (long)grow * DD + slot * 8;
    bdst[r] = lds_b + r * 2048 + w * 512;
  }

  // --- fragment read offsets (u16 units), swizzled ---
  const int l15 = lane & 15, x7 = lane & 7, sA = lane >> 4;
  int aoff[2][4], boff[2][8];
#pragma unroll
  for (int kk = 0; kk < 2; ++kk) {
    const int sl = ((kk * 4 + sA) ^ x7) * 8;
#pragma unroll
    for (int m = 0; m < 4; ++m) aoff[kk][m] = (wr * 64 + m * 16 + l15) * 64 + sl;
#pragma unroll
    for (int n = 0; n < 8; ++n) {
      const int brow = (n < 4) ? (wc * 64 + n * 16 + l15)
                               : (128 + wc * 64 + (n - 4) * 16 + l15);
      boff[kk][n] = brow * 64 + sl;
    }
  }

  f32x4 acc[4][8];
#pragma unroll
  for (int m = 0; m < 4; ++m)
#pragma unroll
    for (int n = 0; n < 8; ++n) acc[m][n] = (f32x4){0.f, 0.f, 0.f, 0.f};

  for (int k0 = 0; k0 < DD; k0 += 64) {
#pragma unroll
    for (int r = 0; r < 4; ++r) gload_lds16(asrc[r] + k0, adst[r]);
#pragma unroll
    for (int r = 0; r < 8; ++r) gload_lds16(bsrc[r] + k0, bdst[r]);
    __syncthreads();

    bf16x8 af[2][4], bfr[2][8];
#pragma unroll
    for (int kk = 0; kk < 2; ++kk) {
#pragma unroll
      for (int m = 0; m < 4; ++m) af[kk][m] = *(const bf16x8*)(lds_a + aoff[kk][m]);
#pragma unroll
      for (int n = 0; n < 8; ++n) bfr[kk][n] = *(const bf16x8*)(lds_b + boff[kk][n]);
    }
#pragma unroll
    for (int m = 0; m < 4; ++m)
#pragma unroll
      for (int n = 0; n < 8; ++n)
#pragma unroll
        for (int kk = 0; kk < 2; ++kk)
          acc[m][n] = __builtin_amdgcn_mfma_f32_16x16x32_bf16(af[kk][m], bfr[kk][n], acc[m][n], 0, 0, 0);
    __syncthreads();
  }

  // epilogue: silu(g)*h in registers (n and n+4 share output col)
#pragma unroll
  for (int m = 0; m < 4; ++m)
#pragma unroll
    for (int n = 0; n < 4; ++n) {
      const int col = j * 128 + wc * 64 + n * 16 + l15;
#pragma unroll
      for (int r = 0; r < 4; ++r) {
        const int row = ts + wr * 64 + m * 16 + sA * 4 + r;
        const float h = acc[m][n][r];
        const float g = acc[m][n + 4][r];
        hb[(long)row * HH + col] = f2bf(h * (g / (1.f + __expf(-g))));
      }
    }
}

// GEMM2: ye[pos,:] = pscale[pos] * (hb[pos,:] @ w2t[e]^T), tile 128x256
// Grid 136x4 (544 = 8*68): XCD k -> j = k>>1, tile-half = k&1. Each XCD reads
// only half of hb (37.5MB) -> total hb fetch ~300MB (was 600).
__global__ __launch_bounds__(256, 2)
void gemm2_kernel(const u16* __restrict__ hb, const u16* __restrict__ w2t,
                  const float* __restrict__ pscale, const int* __restrict__ pofs,
                  u16* __restrict__ ye) {
  __shared__ __align__(16) u16 lds_a[128 * 64];
  __shared__ __align__(16) u16 lds_b[256 * 64];

  const int f = blockIdx.y * 136 + blockIdx.x;
  const int k8 = f & 7, idx = f >> 3;       // idx 0..67
  const int tileIdx = (k8 & 1) * 68 + idx;  // 0..135
  const int j = k8 >> 1;                    // 0..3: out cols [j*256, +256)

  const int ts = tileIdx * 128;
  if (ts >= pofs[EE]) return;
  int e = 0;
#pragma unroll
  for (int i = 1; i < EE; ++i) e += (ts >= pofs[i]) ? 1 : 0;

  const int tid = threadIdx.x;
  const int w = tid >> 6, lane = tid & 63;
  const int wr = w >> 1, wc = w & 1;

  const u16* bbase = w2t + (long)e * ((long)DD * HH);

  const u16* asrc[4]; const u16* bsrc[8];
  u16* adst[4]; u16* bdst[8];
#pragma unroll
  for (int r = 0; r < 4; ++r) {
    const int L = r * 4096 + tid * 16;
    const int row = L >> 7;
    const int slot = ((L >> 4) & 7) ^ (row & 7);
    asrc[r] = hb + (long)(ts + row) * HH + slot * 8;
    adst[r] = lds_a + r * 2048 + w * 512;
  }
#pragma unroll
  for (int r = 0; r < 8; ++r) {
    const int L = r * 4096 + tid * 16;
    const int row = L >> 7;                              // 0..255
    const int slot = ((L >> 4) & 7) ^ (row & 7);
    bsrc[r] = bbase + (long)(j * 256 + row) * HH + slot * 8;
    bdst[r] = lds_b + r * 2048 + w * 512;
  }

  const int l15 = lane & 15, x7 = lane & 7, sA = lane >> 4;
  int aoff[2][4], boff[2][8];
#pragma unroll
  for (int kk = 0; kk < 2; ++kk) {
    const int sl = ((kk * 4 + sA) ^ x7) * 8;
#pragma unroll
    for (int m = 0; m < 4; ++m) aoff[kk][m] = (wr * 64 + m * 16 + l15) * 64 + sl;
#pragma unroll
    for (int n = 0; n < 8; ++n) boff[kk][n] = (wc * 128 + n * 16 + l15) * 64 + sl;
  }

  f32x4 acc[4][8];
#pragma unroll
  for (int m = 0; m < 4; ++m)
#pragma unroll
    for (int n = 0; n < 8; ++n) acc[m][n] = (f32x4){0.f, 0.f, 0.f, 0.f};

  for (int k0 = 0; k0 < HH; k0 += 64) {
#pragma unroll
    for (int r = 0; r < 4; ++r) gload_lds16(asrc[r] + k0, adst[r]);
#pragma unroll
    for (int r = 0; r < 8; ++r) gload_lds16(bsrc[r] + k0, bdst[r]);
    __syncthreads();

    bf16x8 af[2][4], bfr[2][8];
#pragma unroll
    for (int kk = 0; kk < 2; ++kk) {
#pragma unroll
      for (int m = 0; m < 4; ++m) af[kk][m] = *(const bf16x8*)(lds_a + aoff[kk][m]);
#pragma unroll
      for (int n = 0; n < 8; ++n) bfr[kk][n] = *(const bf16x8*)(lds_b + boff[kk][n]);
    }
#pragma unroll
    for (int m = 0; m < 4; ++m)
#pragma unroll
      for (int n = 0; n < 8; ++n)
#pragma unroll
        for (int kk = 0; kk < 2; ++kk)
          acc[m][n] = __builtin_amdgcn_mfma_f32_16x16x32_bf16(af[kk][m], bfr[kk][n], acc[m][n], 0, 0, 0);
    __syncthreads();
  }

#pragma unroll
  for (int m = 0; m < 4; ++m)
#pragma unroll
    for (int r = 0; r < 4; ++r) {
      const int row = ts + wr * 64 + m * 16 + sA * 4 + r;
      const float sc = pscale[row];   // 0.0 for pad rows
#pragma unroll
      for (int n = 0; n < 8; ++n) {
        const int col = j * 256 + wc * 128 + n * 16 + l15;
        ye[(long)row * DD + col] = f2bf(acc[m][n][r] * sc);
      }
    }
}

// ---------------- combine: y[t] = ye[pos0] + ye[pos1] ----------------
__global__ void combine_kernel(const u16* __restrict__ ye, const int* __restrict__ ppos,
                               float* __restrict__ y) {
  const long i = (long)blockIdx.x * 256 + threadIdx.x;  // one thread -> 8 outputs
  const int t = (int)(i >> 7);
  const int c = ((int)i & 127) * 8;
  const int p0 = ppos[t * 2], p1 = ppos[t * 2 + 1];
  u16x8 v0 = *(const u16x8*)(ye + (long)p0 * DD + c);
  u16x8 v1 = *(const u16x8*)(ye + (long)p1 * DD + c);
  f32x4 o0, o1;
  o0[0] = bf2f(v0[0]) + bf2f(v1[0]);
  o0[1] = bf2f(v0[1]) + bf2f(v1[1]);
  o0[2] = bf2f(v0[2]) + bf2f(v1[2]);
  o0[3] = bf2f(v0[3]) + bf2f(v1[3]);
  o1[0] = bf2f(v0[4]) + bf2f(v1[4]);
  o1[1] = bf2f(v0[5]) + bf2f(v1[5]);
  o1[2] = bf2f(v0[6]) + bf2f(v1[6]);
  o1[3] = bf2f(v0[7]) + bf2f(v1[7]);
  *(f32x4*)(y + (long)t * DD + c) = o0;
  *(f32x4*)(y + (long)t * DD + c + 4) = o1;
}

extern "C" void kernel_launch(void* const* d_in, const int* in_sizes, int n_in,
                              void* d_out, int out_size, void* d_ws, size_t ws_size,
                              hipStream_t stream) {
  const float* x    = (const float*)d_in[0];
  const float* ep   = (const float*)d_in[1];
  const int*   eidx = (const int*)d_in[2];
  const float* w13  = (const float*)d_in[3];
  const float* w2   = (const float*)d_in[4];
  float* y = (float*)d_out;

  char* ws = (char*)d_ws;
  size_t off = 0;
  auto alloc = [&](size_t bytes) {
    char* p = ws + off;
    off = (off + bytes + 255) & ~(size_t)255;
    return p;
  };
  u16* xb     = (u16*)alloc((size_t)TT * DD * 2);
  u16* w13t   = (u16*)alloc((size_t)EE * H2 * DD * 2);
  u16* w2t    = (u16*)alloc((size_t)EE * DD * HH * 2);
  u16* hb     = (u16*)alloc((size_t)PADROWS * HH * 2);
  u16* ye     = (u16*)alloc((size_t)PADROWS * DD * 2);
  char* zbase = ws + off;
  int*   ptok   = (int*)alloc((size_t)PADROWS * 4);
  float* pscale = (float*)alloc((size_t)PADROWS * 4);
  int*   cnt    = (int*)alloc(EE * 4);
  int*   cnt2   = (int*)alloc(EE * 4);
  size_t zbytes = (size_t)((ws + off) - zbase);
  int*   pofs   = (int*)alloc((EE + 1) * 4);
  int*   ppos   = (int*)alloc((size_t)PP * 4);
  (void)ws_size; (void)in_sizes; (void)n_in; (void)out_size;

  // zero routing state (pad rows -> token 0, scale 0)
  hipMemsetAsync(zbase, 0, zbytes, stream);

  cast_x_kernel<<<4096, 256, 0, stream>>>(x, xb);
  // w13 [E][1024][4096] -> w13t [E][4096][1024]
  tcast_kernel<<<dim3(H2 / 32, DD / 128, EE), 256, 0, stream>>>(w13, w13t, DD, H2);
  // w2 [E][2048][1024] -> w2t [E][1024][2048]
  tcast_kernel<<<dim3(DD / 32, HH / 128, EE), 256, 0, stream>>>(w2, w2t, HH, DD);

  count_kernel<<<PP / 256, 256, 0, stream>>>(eidx, cnt);
  scan_kernel<<<1, 64, 0, stream>>>(cnt, pofs);
  place_kernel<<<PP / 256, 256, 0, stream>>>(eidx, ep, pofs, cnt2, ptok, pscale, ppos);

  gemm1_kernel<<<dim3(MAXTILES, HH / 128), 256, 0, stream>>>(xb, w13t, ptok, pofs, hb);
  gemm2_kernel<<<dim3(136, 4), 256, 0, stream>>>(hb, w2t, pscale, pofs, ye);
  combine_kernel<<<4096, 256, 0, stream>>>(ye, ppos, y);
}

// Round 8
// 357.617 us; speedup vs baseline: 1.3372x; 1.3372x over previous
//
#include <hip/hip_runtime.h>
#include <cstdint>
#include <cstddef>

// Problem constants (FusedExperts: E=8 TOPK=2, B=2 S=4096 D=1024 H=2048)
#define TT   8192     // tokens = B*S
#define DD   1024     // model dim
#define HH   2048     // hidden dim
#define H2   4096     // 2*H
#define EE   8        // experts
#define PP   16384    // routed pairs = TT*TOPK
#define PADROWS 17280 // max sum of per-expert 128-padded group sizes = 135*128
#define MAXTILES 135

typedef unsigned short u16;
typedef __attribute__((ext_vector_type(8))) short bf16x8;   // 8 bf16 = 4 VGPR (MFMA A/B frag)
typedef __attribute__((ext_vector_type(8))) unsigned short u16x8;
typedef __attribute__((ext_vector_type(4))) float f32x4;    // MFMA C/D frag

__device__ __forceinline__ u16 f2bf(float f) {
  unsigned int u = __builtin_bit_cast(unsigned int, f);
  u += 0x7fffu + ((u >> 16) & 1u);          // round-to-nearest-even
  return (u16)(u >> 16);
}
__device__ __forceinline__ float bf2f(u16 s) {
  unsigned int u = ((unsigned int)s) << 16;
  return __builtin_bit_cast(float, u);
}

__device__ __forceinline__ void gload_lds16(const u16* g, u16* l) {
  __builtin_amdgcn_global_load_lds(
      (const __attribute__((address_space(1))) void*)g,
      (__attribute__((address_space(3))) void*)l, 16, 0, 0);
}

// ============ prep: cast_x + transpose-cast w13/w2 + routing, ONE kernel ============
// Block ranges: [0,4096) cast_x; [4096,12288) tcast w13; [12288,16384) tcast w2;
// [16384] routing (single block, LDS histogram -- replaces 32768 contended
// global atomics with 2x16384 LDS atomics on 8 addresses).
// Row-permutation from atomic ordering does NOT change y bitwise: each hb/ye row
// depends only on (token, expert), and combine gathers through ppos.
__global__ __launch_bounds__(256)
void prep_kernel(const float* __restrict__ x, u16* __restrict__ xb,
                 const float* __restrict__ w13, u16* __restrict__ w13t,
                 const float* __restrict__ w2, u16* __restrict__ w2t,
                 const int* __restrict__ eidx, const float* __restrict__ ep,
                 int* __restrict__ pofs, int* __restrict__ ptok,
                 float* __restrict__ pscale, int* __restrict__ ppos) {
  __shared__ __align__(16) u16 tile[32][140];
  __shared__ int hcnt[EE], hbase[EE], hrun[EE];
  const int b = blockIdx.x;
  const int t = threadIdx.x;

  if (b < 4096) {
    // ---- cast_x: f32 -> bf16, 8 elems/thread ----
    const long i = (long)b * 256 + t;
    const f32x4* s = (const f32x4*)(x + i * 8);
    f32x4 a = s[0], c = s[1];
    u16x8 o;
    o[0]=f2bf(a[0]); o[1]=f2bf(a[1]); o[2]=f2bf(a[2]); o[3]=f2bf(a[3]);
    o[4]=f2bf(c[0]); o[5]=f2bf(c[1]); o[6]=f2bf(c[2]); o[7]=f2bf(c[3]);
    *(u16x8*)(xb + i * 8) = o;
    return;
  }

  if (b < 16384) {
    // ---- transpose-cast: src [E][R][C] f32 -> dst [E][C][R] bf16 ----
    const float* src; u16* dst; int R, C, gx, gy, gz;
    if (b < 12288) {
      const int lb = b - 4096;              // w13: R=DD, C=H2; grid 128x8x8
      src = w13; dst = w13t; R = DD; C = H2;
      gx = lb & 127; gy = (lb >> 7) & 7; gz = lb >> 10;
    } else {
      const int lb = b - 12288;             // w2: R=HH, C=DD; grid 32x16x8
      src = w2; dst = w2t; R = HH; C = DD;
      gx = lb & 31; gy = (lb >> 5) & 15; gz = lb >> 9;
    }
    const long base = (long)gz * (long)R * C;
    const int c0 = gx * 32, r0 = gy * 128;
    {
      const int tx = t & 31, ty = t >> 5;
#pragma unroll
      for (int rr = 0; rr < 16; ++rr) {
        const int r = ty + rr * 8;
        tile[tx][r] = f2bf(src[base + (long)(r0 + r) * C + c0 + tx]);
      }
    }
    __syncthreads();
    {
      const int k = t & 15, cb = t >> 4;
#pragma unroll
      for (int i = 0; i < 2; ++i) {
        const int c = i * 16 + cb;
        u16x8 o = *(const u16x8*)(&tile[c][8 * k]);
        *(u16x8*)(dst + base + (long)(c0 + c) * R + r0 + 8 * k) = o;
      }
    }
    return;
  }

  // ---- routing: single block, 64 pairs/thread ----
  if (t < EE) { hcnt[t] = 0; hrun[t] = 0; }
  __syncthreads();
#pragma unroll 4
  for (int k = 0; k < 64; ++k) {
    const int i = t * 64 + k;
    atomicAdd(&hcnt[eidx[i]], 1);
  }
  __syncthreads();
  if (t == 0) {
    int run = 0;
#pragma unroll
    for (int e = 0; e < EE; ++e) {
      pofs[e] = run; hbase[e] = run;
      run += ((hcnt[e] + 127) >> 7) << 7;
    }
    pofs[EE] = run;
  }
  __syncthreads();
#pragma unroll 4
  for (int k = 0; k < 64; ++k) {
    const int i = t * 64 + k;
    const int e = eidx[i];
    const int r = atomicAdd(&hrun[e], 1);
    const int pos = hbase[e] + r;
    ptok[pos] = i >> 1;         // token index (TOPK=2)
    pscale[pos] = ep[i];
    ppos[i] = pos;
  }
}

// ============ GEMM1: R3-proven 128x128 2-barrier core (174 us best) ============
// LDS tile [128][64] bf16; (row,slot) stored at slot^(row&7). gload_lds writes
// linearly -> per-lane GLOBAL source inverse-swizzled (rule #21). 4 waves 2x2,
// 4x4 frags. T1 XCD swizzle; T2 swizzle -> conflicts == 0 (measured R2-R7).
__global__ __launch_bounds__(256, 2)
void gemm1_kernel(const u16* __restrict__ xb, const u16* __restrict__ w13t,
                  const int* __restrict__ ptok, const int* __restrict__ pofs,
                  u16* __restrict__ hb) {
  __shared__ __align__(16) u16 lds_a[128 * 64];
  __shared__ __align__(16) u16 lds_b[128 * 64];

  // T1 XCD swizzle: nwg = 135*32 = 4320 = 8*540 (exact)
  const int f = blockIdx.y * MAXTILES + blockIdx.x;
  const int wg = (f & 7) * 540 + (f >> 3);
  const int tileIdx = wg % MAXTILES;
  const int j = wg / MAXTILES;                 // h cols [j*64, j*64+64)

  const int ts = tileIdx * 128;
  if (ts >= pofs[EE]) return;
  int e = 0;
#pragma unroll
  for (int i = 1; i < EE; ++i) e += (ts >= pofs[i]) ? 1 : 0;

  const int tid = threadIdx.x;
  const int w = tid >> 6, lane = tid & 63;
  const int wr = w >> 1, wc = w & 1;

  const u16* bbase = w13t + (long)e * ((long)H2 * DD);

  const u16* asrc[4]; const u16* bsrc[4];
  u16* adst[4]; u16* bdst[4];
#pragma unroll
  for (int r = 0; r < 4; ++r) {
    const int L = (r * 4 + w) * 1024 + lane * 16;       // linear LDS byte
    const int row = L >> 7;                              // 128 B per row
    const int slot = ((L >> 4) & 7) ^ (row & 7);         // inverse-swizzled src slot
    asrc[r] = xb + (long)ptok[ts + row] * DD + slot * 8;
    const int gr = (row < 64) ? (j * 64 + row) : (HH + j * 64 + row - 64);
    bsrc[r] = bbase + (long)gr * DD + slot * 8;
    adst[r] = lds_a + (r * 4 + w) * 512;                 // wave-uniform base
    bdst[r] = lds_b + (r * 4 + w) * 512;
  }

  const int rA = wr * 64 + (lane & 15);
  const int sA = lane >> 4;
  const int x7 = lane & 7;
  int aoff[2][4], boff[2][4];
  int rB[4];
  rB[0] = wc * 32 + (lane & 15);
  rB[1] = wc * 32 + 16 + (lane & 15);
  rB[2] = 64 + wc * 32 + (lane & 15);
  rB[3] = 64 + wc * 32 + 16 + (lane & 15);
#pragma unroll
  for (int kk = 0; kk < 2; ++kk) {
    const int sl = ((kk * 4 + sA) ^ x7) * 8;
#pragma unroll
    for (int m = 0; m < 4; ++m) aoff[kk][m] = (rA + m * 16) * 64 + sl;
#pragma unroll
    for (int n = 0; n < 4; ++n) boff[kk][n] = rB[n] * 64 + sl;
  }

  f32x4 acc[4][4];
#pragma unroll
  for (int m = 0; m < 4; ++m)
#pragma unroll
    for (int n = 0; n < 4; ++n) acc[m][n] = (f32x4){0.f, 0.f, 0.f, 0.f};

  for (int k0 = 0; k0 < DD; k0 += 64) {
#pragma unroll
    for (int r = 0; r < 4; ++r) gload_lds16(asrc[r] + k0, adst[r]);
#pragma unroll
    for (int r = 0; r < 4; ++r) gload_lds16(bsrc[r] + k0, bdst[r]);
    __syncthreads();

    bf16x8 af[2][4], bfr[2][4];
#pragma unroll
    for (int kk = 0; kk < 2; ++kk) {
#pragma unroll
      for (int m = 0; m < 4; ++m) af[kk][m] = *(const bf16x8*)(lds_a + aoff[kk][m]);
#pragma unroll
      for (int n = 0; n < 4; ++n) bfr[kk][n] = *(const bf16x8*)(lds_b + boff[kk][n]);
    }
#pragma unroll
    for (int m = 0; m < 4; ++m)
#pragma unroll
      for (int n = 0; n < 4; ++n)
#pragma unroll
        for (int kk = 0; kk < 2; ++kk)
          acc[m][n] = __builtin_amdgcn_mfma_f32_16x16x32_bf16(af[kk][m], bfr[kk][n], acc[m][n], 0, 0, 0);
    __syncthreads();
  }

  // epilogue: silu(g)*h in registers (n-frag pairs (0,2) and (1,3) share cols)
  const int rg = lane >> 4;              // C/D: row = rg*4 + r, col = lane&15
#pragma unroll
  for (int m = 0; m < 4; ++m)
#pragma unroll
    for (int n = 0; n < 2; ++n) {
      const int col = j * 64 + wc * 32 + n * 16 + (lane & 15);
#pragma unroll
      for (int r = 0; r < 4; ++r) {
        const int row = ts + wr * 64 + m * 16 + rg * 4 + r;
        const float h = acc[m][n][r];
        const float g = acc[m][n + 2][r];
        hb[(long)row * HH + col] = f2bf(h * (g / (1.f + __expf(-g))));
      }
    }
}

// ============ GEMM2: 128x256 tile (R7 version -- halves hb re-reads) ============
// Grid 136x4 (544 = 8*68): XCD k -> j = k>>1, tile-half = k&1. Each XCD reads
// only half of hb -> total hb fetch ~300MB (was 600).
__global__ __launch_bounds__(256, 2)
void gemm2_kernel(const u16* __restrict__ hb, const u16* __restrict__ w2t,
                  const float* __restrict__ pscale, const int* __restrict__ pofs,
                  u16* __restrict__ ye) {
  __shared__ __align__(16) u16 lds_a[128 * 64];
  __shared__ __align__(16) u16 lds_b[256 * 64];

  const int f = blockIdx.y * 136 + blockIdx.x;
  const int k8 = f & 7, idx = f >> 3;       // idx 0..67
  const int tileIdx = (k8 & 1) * 68 + idx;  // 0..135
  const int j = k8 >> 1;                    // 0..3: out cols [j*256, +256)

  const int ts = tileIdx * 128;
  if (ts >= pofs[EE]) return;
  int e = 0;
#pragma unroll
  for (int i = 1; i < EE; ++i) e += (ts >= pofs[i]) ? 1 : 0;

  const int tid = threadIdx.x;
  const int w = tid >> 6, lane = tid & 63;
  const int wr = w >> 1, wc = w & 1;

  const u16* bbase = w2t + (long)e * ((long)DD * HH);

  const u16* asrc[4]; const u16* bsrc[8];
  u16* adst[4]; u16* bdst[8];
#pragma unroll
  for (int r = 0; r < 4; ++r) {
    const int L = r * 4096 + tid * 16;
    const int row = L >> 7;
    const int slot = ((L >> 4) & 7) ^ (row & 7);
    asrc[r] = hb + (long)(ts + row) * HH + slot * 8;
    adst[r] = lds_a + r * 2048 + w * 512;
  }
#pragma unroll
  for (int r = 0; r < 8; ++r) {
    const int L = r * 4096 + tid * 16;
    const int row = L >> 7;                              // 0..255
    const int slot = ((L >> 4) & 7) ^ (row & 7);
    bsrc[r] = bbase + (long)(j * 256 + row) * HH + slot * 8;
    bdst[r] = lds_b + r * 2048 + w * 512;
  }

  const int l15 = lane & 15, x7 = lane & 7, sA = lane >> 4;
  int aoff[2][4], boff[2][8];
#pragma unroll
  for (int kk = 0; kk < 2; ++kk) {
    const int sl = ((kk * 4 + sA) ^ x7) * 8;
#pragma unroll
    for (int m = 0; m < 4; ++m) aoff[kk][m] = (wr * 64 + m * 16 + l15) * 64 + sl;
#pragma unroll
    for (int n = 0; n < 8; ++n) boff[kk][n] = (wc * 128 + n * 16 + l15) * 64 + sl;
  }

  f32x4 acc[4][8];
#pragma unroll
  for (int m = 0; m < 4; ++m)
#pragma unroll
    for (int n = 0; n < 8; ++n) acc[m][n] = (f32x4){0.f, 0.f, 0.f, 0.f};

  for (int k0 = 0; k0 < HH; k0 += 64) {
#pragma unroll
    for (int r = 0; r < 4; ++r) gload_lds16(asrc[r] + k0, adst[r]);
#pragma unroll
    for (int r = 0; r < 8; ++r) gload_lds16(bsrc[r] + k0, bdst[r]);
    __syncthreads();

    bf16x8 af[2][4], bfr[2][8];
#pragma unroll
    for (int kk = 0; kk < 2; ++kk) {
#pragma unroll
      for (int m = 0; m < 4; ++m) af[kk][m] = *(const bf16x8*)(lds_a + aoff[kk][m]);
#pragma unroll
      for (int n = 0; n < 8; ++n) bfr[kk][n] = *(const bf16x8*)(lds_b + boff[kk][n]);
    }
#pragma unroll
    for (int m = 0; m < 4; ++m)
#pragma unroll
      for (int n = 0; n < 8; ++n)
#pragma unroll
        for (int kk = 0; kk < 2; ++kk)
          acc[m][n] = __builtin_amdgcn_mfma_f32_16x16x32_bf16(af[kk][m], bfr[kk][n], acc[m][n], 0, 0, 0);
    __syncthreads();
  }

#pragma unroll
  for (int m = 0; m < 4; ++m)
#pragma unroll
    for (int r = 0; r < 4; ++r) {
      const int row = ts + wr * 64 + m * 16 + sA * 4 + r;
      const float sc = pscale[row];   // 0.0 for pad rows
#pragma unroll
      for (int n = 0; n < 8; ++n) {
        const int col = j * 256 + wc * 128 + n * 16 + l15;
        ye[(long)row * DD + col] = f2bf(acc[m][n][r] * sc);
      }
    }
}

// ---------------- combine: y[t] = ye[pos0] + ye[pos1] ----------------
__global__ void combine_kernel(const u16* __restrict__ ye, const int* __restrict__ ppos,
                               float* __restrict__ y) {
  const long i = (long)blockIdx.x * 256 + threadIdx.x;  // one thread -> 8 outputs
  const int t = (int)(i >> 7);
  const int c = ((int)i & 127) * 8;
  const int p0 = ppos[t * 2], p1 = ppos[t * 2 + 1];
  u16x8 v0 = *(const u16x8*)(ye + (long)p0 * DD + c);
  u16x8 v1 = *(const u16x8*)(ye + (long)p1 * DD + c);
  f32x4 o0, o1;
  o0[0] = bf2f(v0[0]) + bf2f(v1[0]);
  o0[1] = bf2f(v0[1]) + bf2f(v1[1]);
  o0[2] = bf2f(v0[2]) + bf2f(v1[2]);
  o0[3] = bf2f(v0[3]) + bf2f(v1[3]);
  o1[0] = bf2f(v0[4]) + bf2f(v1[4]);
  o1[1] = bf2f(v0[5]) + bf2f(v1[5]);
  o1[2] = bf2f(v0[6]) + bf2f(v1[6]);
  o1[3] = bf2f(v0[7]) + bf2f(v1[7]);
  *(f32x4*)(y + (long)t * DD + c) = o0;
  *(f32x4*)(y + (long)t * DD + c + 4) = o1;
}

extern "C" void kernel_launch(void* const* d_in, const int* in_sizes, int n_in,
                              void* d_out, int out_size, void* d_ws, size_t ws_size,
                              hipStream_t stream) {
  const float* x    = (const float*)d_in[0];
  const float* ep   = (const float*)d_in[1];
  const int*   eidx = (const int*)d_in[2];
  const float* w13  = (const float*)d_in[3];
  const float* w2   = (const float*)d_in[4];
  float* y = (float*)d_out;

  char* ws = (char*)d_ws;
  size_t off = 0;
  auto alloc = [&](size_t bytes) {
    char* p = ws + off;
    off = (off + bytes + 255) & ~(size_t)255;
    return p;
  };
  u16* xb     = (u16*)alloc((size_t)TT * DD * 2);
  u16* w13t   = (u16*)alloc((size_t)EE * H2 * DD * 2);
  u16* w2t    = (u16*)alloc((size_t)EE * DD * HH * 2);
  u16* hb     = (u16*)alloc((size_t)PADROWS * HH * 2);
  u16* ye     = (u16*)alloc((size_t)PADROWS * DD * 2);
  char* zbase = ws + off;
  int*   ptok   = (int*)alloc((size_t)PADROWS * 4);
  float* pscale = (float*)alloc((size_t)PADROWS * 4);
  size_t zbytes = (size_t)((ws + off) - zbase);
  int*   pofs   = (int*)alloc((EE + 1) * 4);
  int*   ppos   = (int*)alloc((size_t)PP * 4);
  (void)ws_size; (void)in_sizes; (void)n_in; (void)out_size;

  // zero routing state (pad rows -> token 0, scale 0)
  hipMemsetAsync(zbase, 0, zbytes, stream);

  // fused prep: cast_x + tcast(w13) + tcast(w2) + routing
  prep_kernel<<<16385, 256, 0, stream>>>(x, xb, w13, w13t, w2, w2t,
                                         eidx, ep, pofs, ptok, pscale, ppos);

  gemm1_kernel<<<dim3(MAXTILES, HH / 64), 256, 0, stream>>>(xb, w13t, ptok, pofs, hb);
  gemm2_kernel<<<dim3(136, 4), 256, 0, stream>>>(hb, w2t, pscale, pofs, ye);
  combine_kernel<<<4096, 256, 0, stream>>>(ye, ppos, y);
}